// Round 11
// baseline (247.109 us; speedup 1.0000x reference)
//
#include <hip/hip_runtime.h>
#include <hip/hip_cooperative_groups.h>
#include <math.h>

namespace cg = cooperative_groups;

#define XYD 16
#define ZD 16
#define SS 4096
#define VV 2048
#define BB 8
#define LL 32
#define WW 8
#define VC 32          // v-chunk for smoothing phase
#define SM_STRIDE 257  // LDS tile stride (states dim +1 pad)

#define GUARD_L 16
#define GUARD_R 512
#define EBUF_N (GUARD_L + SS + GUARD_R)  // bf16 elems per buffer (4624)

// Raw workgroup barrier: LDS ordering only (no vmcnt drain of store acks/prefetches).
#define BAR() asm volatile("s_waitcnt lgkmcnt(0)\n\ts_barrier" ::: "memory")

__device__ __forceinline__ float b2f(unsigned short u) {
    union { unsigned int i; float f; } x; x.i = ((unsigned int)u) << 16; return x.f;
}
__device__ __forceinline__ unsigned short f2b(float f) {
    union { float f; unsigned int i; } x; x.f = f; return (unsigned short)(x.i >> 16);
}

// ---------------- Single cooperative kernel: logZ -> smooth -> emis -> forward -------
// 256 blocks x 1024 threads, 1 block/CU.  grid.sync() between phases.
__global__ void __launch_bounds__(1024, 4) k_all(
    const int* __restrict__ stories, const float* __restrict__ trans_w,
    const float* __restrict__ emis_w, const float* __restrict__ prior_w,
    float* __restrict__ out, unsigned short* __restrict__ smTb,
    float* __restrict__ all_emis, float* __restrict__ logZ) {

    __shared__ __align__(16) char shraw[VC * SM_STRIDE * sizeof(float)];  // 32,896 B

    cg::grid_group grid = cg::this_grid();
    int tid = threadIdx.x, bid = blockIdx.x;
    int lane = tid & 63, wid = tid >> 6;

    // ================= Phase A: logZ[row] = logsumexp_V emis_w[row,:] ================
    {
        int row = bid * 16 + wid;                     // 256 blocks * 16 waves = 4096
        const float* r = emis_w + (size_t)row * VV;
        float vals[32];
        float m = -INFINITY;
#pragma unroll
        for (int k = 0; k < 8; k++) {
            float4 f = ((const float4*)r)[k * 64 + lane];
            vals[k*4+0] = f.x; vals[k*4+1] = f.y; vals[k*4+2] = f.z; vals[k*4+3] = f.w;
        }
#pragma unroll
        for (int k = 0; k < 32; k++) m = fmaxf(m, vals[k]);
#pragma unroll
        for (int o = 32; o; o >>= 1) m = fmaxf(m, __shfl_xor(m, o));
        float sum = 0.f;
#pragma unroll
        for (int k = 0; k < 32; k++) sum += __expf(vals[k] - m);
#pragma unroll
        for (int o = 32; o; o >>= 1) sum += __shfl_xor(sum, o);
        if (lane == 0) logZ[row] = m + __logf(sum);
    }
    grid.sync();

    // ================= Phase B: smoothing + transpose, bf16 smT ======================
    {
        float* tileT = (float*)shraw;
        int rsub = tid >> 3;          // 0..127
        int c0   = (tid & 7) * 4;     // 0,4,..,28
        int s    = tid & 255, g = tid >> 8;   // compute-phase mapping
        int x = s & 15, y = s >> 4;
        int sxp = (x < 15) ? s + 1  : s;
        int sxm = (x > 0)  ? s - 1  : s;
        int syp = (y < 15) ? s + 16 : s;
        int sym = (y > 0)  ? s - 16 : s;
#pragma unroll
        for (int c = 0; c < 4; c++) {
            int combo = bid * 4 + c;              // 0..1023
            int z  = combo >> 6;
            int v0 = (combo & 63) * VC;
            __syncthreads();   // tile free from previous iteration
#pragma unroll
            for (int it = 0; it < 2; it++) {
                int r  = it * 128 + rsub;         // plane state 0..255
                int sg = z * 256 + r;
                float lz = logZ[sg];
                float4 w = *(const float4*)(emis_w + (size_t)sg * VV + v0 + c0);
                tileT[(c0+0)*SM_STRIDE + r] = __expf(w.x - lz);
                tileT[(c0+1)*SM_STRIDE + r] = __expf(w.y - lz);
                tileT[(c0+2)*SM_STRIDE + r] = __expf(w.z - lz);
                tileT[(c0+3)*SM_STRIDE + r] = __expf(w.w - lz);
            }
            __syncthreads();
            unsigned short* o = smTb + (size_t)(v0 + g * 8) * SS + z * 256 + s;
#pragma unroll
            for (int i = 0; i < 8; i++) {
                const float* tb = tileT + (g * 8 + i) * SM_STRIDE;
                float sm = tb[s] + tb[sxp] + tb[sxm] + tb[syp] + tb[sym];
                o[(size_t)i * SS] = f2b(__logf(sm * 0.2f));
            }
        }
    }
    grid.sync();

    // ================= Phase C: all_emis[t,b,s] = sum_w smT[tok][s] ==================
    {
        int t = bid >> 3, b = bid & 7;
        int tok[WW];
#pragma unroll
        for (int w = 0; w < WW; w++) tok[w] = stories[(b * LL + t) * WW + w];
        int s0 = tid * 4;
        float4 acc = {0.f, 0.f, 0.f, 0.f};
#pragma unroll
        for (int w = 0; w < WW; w++) {
            if (tok[w] < VV) {  // wave-uniform
                ushort4 u = *(const ushort4*)(smTb + (size_t)tok[w] * SS + s0);
                acc.x += b2f(u.x); acc.y += b2f(u.y);
                acc.z += b2f(u.z); acc.w += b2f(u.w);
            }
        }
        *(float4*)(all_emis + ((size_t)t * BB + b) * SS + s0) = acc;
    }
    grid.sync();

    // ================= Phase D: forward recurrence (blocks 0..7) =====================
    if (bid >= BB) return;
    {
        unsigned short* Eb0 = (unsigned short*)shraw;      // [EBUF_N]
        unsigned short* Eb1 = Eb0 + EBUF_N;
        float* red2 = (float*)(shraw + 4 * EBUF_N);        // [2]
        float* pr   = red2 + 2;                            // [16]
        int b = bid;

        if (tid < GUARD_L) { Eb0[tid] = 0; Eb1[tid] = 0; }
        if (tid < GUARD_R) {
            Eb0[GUARD_L + SS + tid] = 0;
            Eb1[GUARD_L + SS + tid] = 0;
        }

        // transition prologue: pw (geometric order), am per state
        float pw[28], am[4];
        {
            float w7[28];
            const float4* t4 = (const float4*)(trans_w + (size_t)tid * 28);
#pragma unroll
            for (int k = 0; k < 7; k++) ((float4*)w7)[k] = t4[k];
#pragma unroll
            for (int i = 0; i < 4; i++) {
                int j = tid * 4 + i;
                int xx = j & 15, yy = (j >> 4) & 15, zz = j >> 8;
                bool val[7];
                val[0] = true;
                val[1] = (xx < 15); val[2] = (xx > 0);
                val[3] = (yy < 15); val[4] = (yy > 0);
                val[5] = (zz < 15); val[6] = (zz < 14);
                const float* rw = w7 + i * 7;
                float w[7]; int cnt = 0; float m = -INFINITY;
#pragma unroll
                for (int d = 0; d < 7; d++) { if (val[d]) { w[d] = rw[cnt++]; m = fmaxf(m, w[d]); } }
                float se = 0.f;
#pragma unroll
                for (int d = 0; d < 7; d++) if (val[d]) se += __expf(w[d] - m);
#pragma unroll
                for (int d = 0; d < 7; d++) pw[i*7+d] = val[d] ? __expf(w[d] - m) : 0.f;
                am[i] = -__logf(se);
            }
        }

        float4 pv = ((const float4*)prior_w)[tid];
        const float4* emp = (const float4*)(all_emis + (size_t)b * SS) + tid;
        float4 em = *emp;   // t=0

        // priors log-softmax denominator
        float lm = fmaxf(fmaxf(pv.x, pv.y), fmaxf(pv.z, pv.w));
#pragma unroll
        for (int o = 32; o; o >>= 1) lm = fmaxf(lm, __shfl_xor(lm, o));
        if (lane == 0) pr[wid] = lm;
        __syncthreads();
        float gm = pr[0];
#pragma unroll
        for (int w = 1; w < 16; w++) gm = fmaxf(gm, pr[w]);
        __syncthreads();
        float ls = __expf(pv.x - gm) + __expf(pv.y - gm) + __expf(pv.z - gm) + __expf(pv.w - gm);
#pragma unroll
        for (int o = 32; o; o >>= 1) ls += __shfl_xor(ls, o);
        if (lane == 0) pr[wid] = ls;
        __syncthreads();
        float gs = 0.f;
#pragma unroll
        for (int w = 0; w < 16; w++) gs += pr[w];
        float logZp = gm + __logf(gs);

        // step 0
        float v0 = em.x + pv.x - logZp;
        float v1 = em.y + pv.y - logZp;
        float v2 = em.z + pv.z - logZp;
        float v3 = em.w + pv.w - logZp;
        float4 ov_prev = {v0, v1, v2, v3};
        float4* outp = (float4*)(out + (size_t)b * SS) + tid;  // slot for t=0

        if (tid == 0) red2[0] = v0;   // g_0
        __syncthreads();
        float g1 = red2[0];
        float XpPrev = g1;            // X_0
        float E0 = __expf(v0 - XpPrev), E1 = __expf(v1 - XpPrev);
        float E2 = __expf(v2 - XpPrev), E3 = __expf(v3 - XpPrev);
        {
            ushort4 E;
            E.x = f2b(E0); E.y = f2b(E1); E.z = f2b(E2); E.w = f2b(E3);
            *(ushort4*)(&Eb0[GUARD_L + 4 * tid]) = E;
        }

        emp += (BB * SS) / 4;
        float4 em_next = *emp;   // t=1

        unsigned short* Ec = Eb0;
        unsigned short* En = Eb1;
        int cur = 0;
        for (int t = 1; t < LL; t++) {
            BAR();
            em = em_next;
            if (t < LL - 1) { emp += (BB * SS) / 4; em_next = *emp; }

            float g0 = red2[cur];                // g_{t-1}
            float Xp = 2.f * g0 - g1;            // X_t
            float dX = XpPrev - Xp;
            float F0 = __expf(em.x + am[0] + dX);
            float F1 = __expf(em.y + am[1] + dX);
            float F2 = __expf(em.z + am[2] + dX);
            float F3 = __expf(em.w + am[3] + dX);

            *outp = ov_prev;                     // pipelined store of v_{t-1}
            outp += (BB * SS) / 4;

            const unsigned short* Eg = Ec + GUARD_L + 4 * tid;
            ushort4 YpU = *(const ushort4*)(Eg + 16);
            ushort4 YmU = *(const ushort4*)(Eg - 16);
            ushort4 ZpU = *(const ushort4*)(Eg + 256);
            ushort4 ZqU = *(const ushort4*)(Eg + 512);
            float bx  = b2f(Eg[4]);
            float cxw = b2f(Eg[-1]);

            float a0 = E0*pw[0]  + E1*pw[1]  + cxw*pw[2] + b2f(YpU.x)*pw[3]  + b2f(YmU.x)*pw[4]  + b2f(ZpU.x)*pw[5]  + b2f(ZqU.x)*pw[6];
            float a1 = E1*pw[7]  + E2*pw[8]  + E0*pw[9]  + b2f(YpU.y)*pw[10] + b2f(YmU.y)*pw[11] + b2f(ZpU.y)*pw[12] + b2f(ZqU.y)*pw[13];
            float a2 = E2*pw[14] + E3*pw[15] + E1*pw[16] + b2f(YpU.z)*pw[17] + b2f(YmU.z)*pw[18] + b2f(ZpU.z)*pw[19] + b2f(ZqU.z)*pw[20];
            float a3 = E3*pw[21] + bx*pw[22] + E2*pw[23] + b2f(YpU.w)*pw[24] + b2f(YmU.w)*pw[25] + b2f(ZpU.w)*pw[26] + b2f(ZqU.w)*pw[27];

            // next-state E via F (no transcendental on this path)
            E0 = a0 * F0; E1 = a1 * F1; E2 = a2 * F2; E3 = a3 * F3;
            {
                ushort4 E;
                E.x = f2b(E0); E.y = f2b(E1); E.z = f2b(E2); E.w = f2b(E3);
                *(ushort4*)(&En[GUARD_L + 4 * tid]) = E;
            }
            float lg0 = __logf(a0);
            if (tid == 0) red2[cur ^ 1] = em.x + lg0 + XpPrev + am[0];  // g_t

            ov_prev.x = em.x + lg0        + XpPrev + am[0];
            ov_prev.y = em.y + __logf(a1) + XpPrev + am[1];
            ov_prev.z = em.z + __logf(a2) + XpPrev + am[2];
            ov_prev.w = em.w + __logf(a3) + XpPrev + am[3];

            g1 = g0; XpPrev = Xp; cur ^= 1;
            unsigned short* tmp = Ec; Ec = En; En = tmp;
        }
        *outp = ov_prev;   // t = LL-1
    }
}

extern "C" void kernel_launch(void* const* d_in, const int* in_sizes, int n_in,
                              void* d_out, int out_size, void* d_ws, size_t ws_size,
                              hipStream_t stream) {
    const int*   stories = (const int*)d_in[0];
    const float* trans_w = (const float*)d_in[2];
    const float* emis_w  = (const float*)d_in[3];
    const float* prior_w = (const float*)d_in[4];
    float* out = (float*)d_out;

    char* ws = (char*)d_ws;
    unsigned short* smTb = (unsigned short*)(ws);                          // 16 MB bf16
    float* all_emis = (float*)(ws + (size_t)VV * SS * 2);                  // 4 MB
    float* logZ     = (float*)(ws + (size_t)VV * SS * 2 + (size_t)LL * BB * SS * 4);  // 16 KB

    void* args[] = { (void*)&stories, (void*)&trans_w, (void*)&emis_w, (void*)&prior_w,
                     (void*)&out, (void*)&smTb, (void*)&all_emis, (void*)&logZ };
    hipLaunchCooperativeKernel((const void*)k_all, dim3(256), dim3(1024), args, 0, stream);
}

// Round 12
// 153.197 us; speedup vs baseline: 1.6130x; 1.6130x over previous
//
#include <hip/hip_runtime.h>
#include <math.h>

#define XYD 16
#define ZD 16
#define SS 4096
#define VV 2048
#define BB 8
#define LL 32
#define WW 8
#define VC 32          // v-chunk for smoothing kernel
#define SM_STRIDE 257  // LDS tile stride (states dim +1 pad)

#define GUARD_L 16
#define GUARD_R 512
#define EBUF_N (GUARD_L + SS + GUARD_R)  // bf16 elems per buffer

// Raw workgroup barrier: LDS ordering only (no vmcnt drain of store acks/prefetches).
#define BAR() asm volatile("s_waitcnt lgkmcnt(0)\n\ts_barrier" ::: "memory")

typedef unsigned short us8 __attribute__((ext_vector_type(8)));

__device__ __forceinline__ float b2f(unsigned short u) {
    union { unsigned int i; float f; } x; x.i = ((unsigned int)u) << 16; return x.f;
}
__device__ __forceinline__ unsigned short f2b(float f) {
    union { float f; unsigned int i; } x; x.f = f; return (unsigned short)(x.i >> 16);
}

// ---------------- Kernel 1: logZ[s] = logsumexp over V of emis_w[s,:] ----------------
__global__ void k_logZ(const float* __restrict__ emis_w, float* __restrict__ logZ) {
    int wave = threadIdx.x >> 6;
    int lane = threadIdx.x & 63;
    int row  = blockIdx.x * 4 + wave;
    const float* r = emis_w + (size_t)row * VV;
    float vals[32];
    float m = -INFINITY;
#pragma unroll
    for (int k = 0; k < 8; k++) {
        float4 f = ((const float4*)r)[k * 64 + lane];
        vals[k*4+0] = f.x; vals[k*4+1] = f.y; vals[k*4+2] = f.z; vals[k*4+3] = f.w;
    }
#pragma unroll
    for (int k = 0; k < 32; k++) m = fmaxf(m, vals[k]);
#pragma unroll
    for (int o = 32; o; o >>= 1) m = fmaxf(m, __shfl_xor(m, o));
    float sum = 0.f;
#pragma unroll
    for (int k = 0; k < 32; k++) sum += __expf(vals[k] - m);
#pragma unroll
    for (int o = 32; o; o >>= 1) sum += __shfl_xor(sum, o);
    if (lane == 0) logZ[row] = m + __logf(sum);
}

// ---------------- Kernel 2: smoothing + transpose, bf16 output -----------------------
__global__ void k_smooth(const float* __restrict__ emis_w, const float* __restrict__ logZ,
                         unsigned short* __restrict__ smTb) {
    __shared__ float tileT[VC * SM_STRIDE];  // [v][state]
    int z  = blockIdx.x;
    int v0 = blockIdx.y * VC;
    int tid = threadIdx.x;
    int rsub = tid >> 3;        // 0..31
    int c0   = (tid & 7) * 4;   // 0,4,..,28

#pragma unroll
    for (int it = 0; it < 8; it++) {
        int r  = it * 32 + rsub;         // plane state 0..255
        int sg = z * 256 + r;
        float lz = logZ[sg];
        float4 w = *(const float4*)(emis_w + (size_t)sg * VV + v0 + c0);
        tileT[(c0+0)*SM_STRIDE + r] = __expf(w.x - lz);
        tileT[(c0+1)*SM_STRIDE + r] = __expf(w.y - lz);
        tileT[(c0+2)*SM_STRIDE + r] = __expf(w.z - lz);
        tileT[(c0+3)*SM_STRIDE + r] = __expf(w.w - lz);
    }
    __syncthreads();

    int x = tid & 15, y = tid >> 4;
    int sxp = (x < 15) ? tid + 1  : tid;
    int sxm = (x > 0)  ? tid - 1  : tid;
    int syp = (y < 15) ? tid + 16 : tid;
    int sym = (y > 0)  ? tid - 16 : tid;
    unsigned short* o = smTb + (size_t)v0 * SS + z * 256 + tid;
#pragma unroll
    for (int i = 0; i < VC; i++) {
        const float* tb = tileT + i * SM_STRIDE;
        float s = tb[tid] + tb[sxp] + tb[sxm] + tb[syp] + tb[sym];
        o[(size_t)i * SS] = f2b(__logf(s * 0.2f));
    }
}

// ---------------- Kernel 3: all_emis[t,b,s] = sum_w smoothedT[tok][s] ----------------
// 256 blocks (t*B+b), 512 threads, 8 states/thread; bf16 smT input
__global__ void __launch_bounds__(512) k_emis(
    const int* __restrict__ stories, const unsigned short* __restrict__ smTb,
    float* __restrict__ all_emis) {
    int blk = blockIdx.x;
    int t = blk >> 3, b = blk & 7;
    int tid = threadIdx.x;
    int tok[WW];
#pragma unroll
    for (int w = 0; w < WW; w++) tok[w] = stories[(b * LL + t) * WW + w];
    int s0 = tid * 8;
    float acc[8] = {0.f,0.f,0.f,0.f,0.f,0.f,0.f,0.f};
#pragma unroll
    for (int w = 0; w < WW; w++) {
        if (tok[w] < VV) {  // wave-uniform
            us8 u = *(const us8*)(smTb + (size_t)tok[w] * SS + s0);
#pragma unroll
            for (int i = 0; i < 8; i++) acc[i] += b2f(u[i]);
        }
    }
    float* dst = all_emis + ((size_t)t * BB + b) * SS + s0;
    float4 lo = {acc[0], acc[1], acc[2], acc[3]};
    float4 hi = {acc[4], acc[5], acc[6], acc[7]};
    ((float4*)dst)[0] = lo;
    ((float4*)dst)[1] = hi;
}

// ---------------- Kernel 4: forward recurrence ---------------------------------------
// One block per batch; 1024 threads, 4 consecutive states/thread (16 waves).
// bf16 Ebuf (R7 best: fewest conflicts) + F-shadow (R9: E_t = a_t * F_t, exps/logs
// off the barrier-to-barrier chain).  Raw lgkmcnt barrier; out-store one step behind.
__global__ void __launch_bounds__(1024) k_forward(
    const float* __restrict__ trans_w, const float* __restrict__ prior_w,
    const float* __restrict__ all_emis, float* __restrict__ out) {
    __shared__ __align__(16) unsigned short Ebuf[2][EBUF_N];
    __shared__ float red2[2];
    __shared__ float pr[16];
    int b = blockIdx.x;
    int tid = threadIdx.x;
    int lane = tid & 63, wid = tid >> 6;

    if (tid < GUARD_L) { Ebuf[0][tid] = 0; Ebuf[1][tid] = 0; }
    if (tid < GUARD_R) {
        Ebuf[0][GUARD_L + SS + tid] = 0;
        Ebuf[1][GUARD_L + SS + tid] = 0;
    }

    // ---- transition prologue: pw (geometric order), am per state ----
    float pw[28], am[4];
    {
        float w7[28];
        const float4* t4 = (const float4*)(trans_w + (size_t)tid * 28);
#pragma unroll
        for (int k = 0; k < 7; k++) ((float4*)w7)[k] = t4[k];
#pragma unroll
        for (int i = 0; i < 4; i++) {
            int j = tid * 4 + i;
            int xx = j & 15, yy = (j >> 4) & 15, zz = j >> 8;
            bool val[7];
            val[0] = true;
            val[1] = (xx < 15); val[2] = (xx > 0);
            val[3] = (yy < 15); val[4] = (yy > 0);
            val[5] = (zz < 15); val[6] = (zz < 14);
            const float* rw = w7 + i * 7;
            float w[7]; int cnt = 0; float m = -INFINITY;
#pragma unroll
            for (int d = 0; d < 7; d++) { if (val[d]) { w[d] = rw[cnt++]; m = fmaxf(m, w[d]); } }
            float se = 0.f;
#pragma unroll
            for (int d = 0; d < 7; d++) if (val[d]) se += __expf(w[d] - m);
#pragma unroll
            for (int d = 0; d < 7; d++) pw[i*7+d] = val[d] ? __expf(w[d] - m) : 0.f;
            am[i] = -__logf(se);
        }
    }

    float4 pv = ((const float4*)prior_w)[tid];
    const float4* emp = (const float4*)(all_emis + (size_t)b * SS) + tid;
    float4 em = *emp;   // t=0

    // ---- priors log-softmax denominator ----
    float lm = fmaxf(fmaxf(pv.x, pv.y), fmaxf(pv.z, pv.w));
#pragma unroll
    for (int o = 32; o; o >>= 1) lm = fmaxf(lm, __shfl_xor(lm, o));
    if (lane == 0) pr[wid] = lm;
    __syncthreads();
    float gm = pr[0];
#pragma unroll
    for (int w = 1; w < 16; w++) gm = fmaxf(gm, pr[w]);
    __syncthreads();
    float ls = __expf(pv.x - gm) + __expf(pv.y - gm) + __expf(pv.z - gm) + __expf(pv.w - gm);
#pragma unroll
    for (int o = 32; o; o >>= 1) ls += __shfl_xor(ls, o);
    if (lane == 0) pr[wid] = ls;
    __syncthreads();
    float gs = 0.f;
#pragma unroll
    for (int w = 0; w < 16; w++) gs += pr[w];
    float logZp = gm + __logf(gs);

    // ---- step 0 ----
    float v0 = em.x + pv.x - logZp;
    float v1 = em.y + pv.y - logZp;
    float v2 = em.z + pv.z - logZp;
    float v3 = em.w + pv.w - logZp;
    float4 ov_prev = {v0, v1, v2, v3};
    float4* outp = (float4*)(out + (size_t)b * SS) + tid;  // slot for t=0

    if (tid == 0) red2[0] = v0;   // g_0
    __syncthreads();
    float g1 = red2[0];
    float XpPrev = g1;            // X_0
    float E0 = __expf(v0 - XpPrev), E1 = __expf(v1 - XpPrev);
    float E2 = __expf(v2 - XpPrev), E3 = __expf(v3 - XpPrev);
    {
        ushort4 E;
        E.x = f2b(E0); E.y = f2b(E1); E.z = f2b(E2); E.w = f2b(E3);
        *(ushort4*)(&Ebuf[0][GUARD_L + 4 * tid]) = E;
    }

    emp += (BB * SS) / 4;
    float4 em_next = *emp;   // t=1

    // ---- steps 1..L-1: one raw barrier per step ----
    int cur = 0;
    for (int t = 1; t < LL; t++) {
        BAR();
        em = em_next;                        // em_t (prefetched one step ago)
        if (t < LL - 1) { emp += (BB * SS) / 4; em_next = *emp; }

        float g0 = red2[cur];                // g_{t-1}
        float Xp = 2.f * g0 - g1;            // X_t
        float dX = XpPrev - Xp;
        // F_t in the gather shadow
        float F0 = __expf(em.x + am[0] + dX);
        float F1 = __expf(em.y + am[1] + dX);
        float F2 = __expf(em.z + am[2] + dX);
        float F3 = __expf(em.w + am[3] + dX);

        *outp = ov_prev;                     // pipelined store of v_{t-1}
        outp += (BB * SS) / 4;

        const unsigned short* Eb = Ebuf[cur] + GUARD_L + 4 * tid;
        ushort4 YpU = *(const ushort4*)(Eb + 16);
        ushort4 YmU = *(const ushort4*)(Eb - 16);
        ushort4 ZpU = *(const ushort4*)(Eb + 256);
        ushort4 ZqU = *(const ushort4*)(Eb + 512);
        float bx  = b2f(Eb[4]);
        float cxw = b2f(Eb[-1]);

        float a0 = E0*pw[0]  + E1*pw[1]  + cxw*pw[2] + b2f(YpU.x)*pw[3]  + b2f(YmU.x)*pw[4]  + b2f(ZpU.x)*pw[5]  + b2f(ZqU.x)*pw[6];
        float a1 = E1*pw[7]  + E2*pw[8]  + E0*pw[9]  + b2f(YpU.y)*pw[10] + b2f(YmU.y)*pw[11] + b2f(ZpU.y)*pw[12] + b2f(ZqU.y)*pw[13];
        float a2 = E2*pw[14] + E3*pw[15] + E1*pw[16] + b2f(YpU.z)*pw[17] + b2f(YmU.z)*pw[18] + b2f(ZpU.z)*pw[19] + b2f(ZqU.z)*pw[20];
        float a3 = E3*pw[21] + bx*pw[22] + E2*pw[23] + b2f(YpU.w)*pw[24] + b2f(YmU.w)*pw[25] + b2f(ZpU.w)*pw[26] + b2f(ZqU.w)*pw[27];

        // next-state E via F (no transcendental on the chain)
        E0 = a0 * F0; E1 = a1 * F1; E2 = a2 * F2; E3 = a3 * F3;
        {
            ushort4 E;
            E.x = f2b(E0); E.y = f2b(E1); E.z = f2b(E2); E.w = f2b(E3);
            *(ushort4*)(&Ebuf[cur ^ 1][GUARD_L + 4 * tid]) = E;
        }
        float lg0 = __logf(a0);
        if (tid == 0) red2[cur ^ 1] = em.x + lg0 + XpPrev + am[0];  // g_t

        // shadow work: outputs v_t for next step's pipelined store
        ov_prev.x = em.x + lg0        + XpPrev + am[0];
        ov_prev.y = em.y + __logf(a1) + XpPrev + am[1];
        ov_prev.z = em.z + __logf(a2) + XpPrev + am[2];
        ov_prev.w = em.w + __logf(a3) + XpPrev + am[3];

        g1 = g0; XpPrev = Xp; cur ^= 1;
    }
    *outp = ov_prev;   // t = LL-1
}

extern "C" void kernel_launch(void* const* d_in, const int* in_sizes, int n_in,
                              void* d_out, int out_size, void* d_ws, size_t ws_size,
                              hipStream_t stream) {
    const int*   stories = (const int*)d_in[0];
    const float* trans_w = (const float*)d_in[2];
    const float* emis_w  = (const float*)d_in[3];
    const float* prior_w = (const float*)d_in[4];
    float* out = (float*)d_out;

    char* ws = (char*)d_ws;
    unsigned short* smTb = (unsigned short*)(ws);                          // 16 MB bf16
    float* all_emis = (float*)(ws + (size_t)VV * SS * 2);                  // 4 MB
    float* logZ     = (float*)(ws + (size_t)VV * SS * 2 + (size_t)LL * BB * SS * 4);  // 16 KB

    k_logZ<<<SS / 4, 256, 0, stream>>>(emis_w, logZ);
    k_smooth<<<dim3(ZD, VV / VC), 256, 0, stream>>>(emis_w, logZ, smTb);
    k_emis<<<LL * BB, 512, 0, stream>>>(stories, smTb, all_emis);
    k_forward<<<BB, 1024, 0, stream>>>(trans_w, prior_w, all_emis, out);
}

// Round 13
// 149.261 us; speedup vs baseline: 1.6556x; 1.0264x over previous
//
#include <hip/hip_runtime.h>
#include <math.h>

#define XYD 16
#define ZD 16
#define SS 4096
#define VV 2048
#define BB 8
#define LL 32
#define WW 8
#define VC 32          // v-chunk for smoothing kernel
#define SM_STRIDE 257  // LDS tile stride (states dim +1 pad)

#define GUARD_L 16
#define GUARD_R 512
#define EBUF_N (GUARD_L + SS + GUARD_R)  // bf16 elems per buffer

// Raw workgroup barrier: LDS ordering only (no vmcnt drain of store acks/prefetches).
#define BAR() asm volatile("s_waitcnt lgkmcnt(0)\n\ts_barrier" ::: "memory")

typedef unsigned short us8 __attribute__((ext_vector_type(8)));

__device__ __forceinline__ float b2f(unsigned short u) {
    union { unsigned int i; float f; } x; x.i = ((unsigned int)u) << 16; return x.f;
}
__device__ __forceinline__ unsigned short f2b(float f) {
    union { float f; unsigned int i; } x; x.f = f; return (unsigned short)(x.i >> 16);
}

// ---------------- Kernel 1: logZ[s] = logsumexp over V of emis_w[s,:] ----------------
__global__ void k_logZ(const float* __restrict__ emis_w, float* __restrict__ logZ) {
    int wave = threadIdx.x >> 6;
    int lane = threadIdx.x & 63;
    int row  = blockIdx.x * 4 + wave;
    const float* r = emis_w + (size_t)row * VV;
    float vals[32];
    float m = -INFINITY;
#pragma unroll
    for (int k = 0; k < 8; k++) {
        float4 f = ((const float4*)r)[k * 64 + lane];
        vals[k*4+0] = f.x; vals[k*4+1] = f.y; vals[k*4+2] = f.z; vals[k*4+3] = f.w;
    }
#pragma unroll
    for (int k = 0; k < 32; k++) m = fmaxf(m, vals[k]);
#pragma unroll
    for (int o = 32; o; o >>= 1) m = fmaxf(m, __shfl_xor(m, o));
    float sum = 0.f;
#pragma unroll
    for (int k = 0; k < 32; k++) sum += __expf(vals[k] - m);
#pragma unroll
    for (int o = 32; o; o >>= 1) sum += __shfl_xor(sum, o);
    if (lane == 0) logZ[row] = m + __logf(sum);
}

// ---------------- Kernel 2: smoothing + transpose, bf16 output -----------------------
__global__ void k_smooth(const float* __restrict__ emis_w, const float* __restrict__ logZ,
                         unsigned short* __restrict__ smTb) {
    __shared__ float tileT[VC * SM_STRIDE];  // [v][state]
    int z  = blockIdx.x;
    int v0 = blockIdx.y * VC;
    int tid = threadIdx.x;
    int rsub = tid >> 3;        // 0..31
    int c0   = (tid & 7) * 4;   // 0,4,..,28

#pragma unroll
    for (int it = 0; it < 8; it++) {
        int r  = it * 32 + rsub;         // plane state 0..255
        int sg = z * 256 + r;
        float lz = logZ[sg];
        float4 w = *(const float4*)(emis_w + (size_t)sg * VV + v0 + c0);
        tileT[(c0+0)*SM_STRIDE + r] = __expf(w.x - lz);
        tileT[(c0+1)*SM_STRIDE + r] = __expf(w.y - lz);
        tileT[(c0+2)*SM_STRIDE + r] = __expf(w.z - lz);
        tileT[(c0+3)*SM_STRIDE + r] = __expf(w.w - lz);
    }
    __syncthreads();

    int x = tid & 15, y = tid >> 4;
    int sxp = (x < 15) ? tid + 1  : tid;
    int sxm = (x > 0)  ? tid - 1  : tid;
    int syp = (y < 15) ? tid + 16 : tid;
    int sym = (y > 0)  ? tid - 16 : tid;
    unsigned short* o = smTb + (size_t)v0 * SS + z * 256 + tid;
#pragma unroll
    for (int i = 0; i < VC; i++) {
        const float* tb = tileT + i * SM_STRIDE;
        float s = tb[tid] + tb[sxp] + tb[sxm] + tb[syp] + tb[sym];
        o[(size_t)i * SS] = f2b(__logf(s * 0.2f));
    }
}

// ---------------- Kernel 3: all_emis[t,b,s] = sum_w smoothedT[tok][s] ----------------
// 256 blocks (t*B+b), 512 threads, 8 states/thread; bf16 smT input
__global__ void __launch_bounds__(512) k_emis(
    const int* __restrict__ stories, const unsigned short* __restrict__ smTb,
    float* __restrict__ all_emis) {
    int blk = blockIdx.x;
    int t = blk >> 3, b = blk & 7;
    int tid = threadIdx.x;
    int tok[WW];
#pragma unroll
    for (int w = 0; w < WW; w++) tok[w] = stories[(b * LL + t) * WW + w];
    int s0 = tid * 8;
    float acc[8] = {0.f,0.f,0.f,0.f,0.f,0.f,0.f,0.f};
#pragma unroll
    for (int w = 0; w < WW; w++) {
        if (tok[w] < VV) {  // wave-uniform
            us8 u = *(const us8*)(smTb + (size_t)tok[w] * SS + s0);
#pragma unroll
            for (int i = 0; i < 8; i++) acc[i] += b2f(u[i]);
        }
    }
    float* dst = all_emis + ((size_t)t * BB + b) * SS + s0;
    float4 lo = {acc[0], acc[1], acc[2], acc[3]};
    float4 hi = {acc[4], acc[5], acc[6], acc[7]};
    ((float4*)dst)[0] = lo;
    ((float4*)dst)[1] = hi;
}

// ---------------- Kernel 4: forward recurrence (exact R7 structure) ------------------
// One block per batch; 1024 threads, 4 consecutive states/thread (16 waves).
// Predicted global frame Xp_t = 2*g_{t-1} - g_{t-2} (g = v[state 0], no reduction).
// bf16 Ebuf; raw lgkmcnt-only barrier; out-store pipelined one step behind.
__global__ void __launch_bounds__(1024) k_forward(
    const float* __restrict__ trans_w, const float* __restrict__ prior_w,
    const float* __restrict__ all_emis, float* __restrict__ out) {
    __shared__ __align__(16) unsigned short Ebuf[2][EBUF_N];
    __shared__ float red2[2];
    __shared__ float pr[16];
    int b = blockIdx.x;
    int tid = threadIdx.x;
    int lane = tid & 63, wid = tid >> 6;

    if (tid < GUARD_L) { Ebuf[0][tid] = 0; Ebuf[1][tid] = 0; }
    if (tid < GUARD_R) {
        Ebuf[0][GUARD_L + SS + tid] = 0;
        Ebuf[1][GUARD_L + SS + tid] = 0;
    }

    // ---- transition prologue: pw (geometric order), am per state ----
    float pw[28], am[4];
    {
        float w7[28];
        const float4* t4 = (const float4*)(trans_w + (size_t)tid * 28);
#pragma unroll
        for (int k = 0; k < 7; k++) ((float4*)w7)[k] = t4[k];
#pragma unroll
        for (int i = 0; i < 4; i++) {
            int j = tid * 4 + i;
            int xx = j & 15, yy = (j >> 4) & 15, zz = j >> 8;
            bool val[7];
            val[0] = true;
            val[1] = (xx < 15); val[2] = (xx > 0);
            val[3] = (yy < 15); val[4] = (yy > 0);
            val[5] = (zz < 15); val[6] = (zz < 14);
            const float* rw = w7 + i * 7;
            float w[7]; int cnt = 0; float m = -INFINITY;
#pragma unroll
            for (int d = 0; d < 7; d++) { if (val[d]) { w[d] = rw[cnt++]; m = fmaxf(m, w[d]); } }
            float se = 0.f;
#pragma unroll
            for (int d = 0; d < 7; d++) if (val[d]) se += __expf(w[d] - m);
#pragma unroll
            for (int d = 0; d < 7; d++) pw[i*7+d] = val[d] ? __expf(w[d] - m) : 0.f;
            am[i] = -__logf(se);
        }
    }

    float4 pv = ((const float4*)prior_w)[tid];
    const float4* emp = (const float4*)(all_emis + (size_t)b * SS) + tid;
    float4 em = *emp;   // t=0

    // ---- priors log-softmax denominator ----
    float lm = fmaxf(fmaxf(pv.x, pv.y), fmaxf(pv.z, pv.w));
#pragma unroll
    for (int o = 32; o; o >>= 1) lm = fmaxf(lm, __shfl_xor(lm, o));
    if (lane == 0) pr[wid] = lm;
    __syncthreads();
    float gm = pr[0];
#pragma unroll
    for (int w = 1; w < 16; w++) gm = fmaxf(gm, pr[w]);
    __syncthreads();
    float ls = __expf(pv.x - gm) + __expf(pv.y - gm) + __expf(pv.z - gm) + __expf(pv.w - gm);
#pragma unroll
    for (int o = 32; o; o >>= 1) ls += __shfl_xor(ls, o);
    if (lane == 0) pr[wid] = ls;
    __syncthreads();
    float gs = 0.f;
#pragma unroll
    for (int w = 0; w < 16; w++) gs += pr[w];
    float logZp = gm + __logf(gs);

    // ---- step 0 (store deferred into loop) ----
    float v0 = em.x + pv.x - logZp;
    float v1 = em.y + pv.y - logZp;
    float v2 = em.z + pv.z - logZp;
    float v3 = em.w + pv.w - logZp;
    float4 ov_prev = {v0, v1, v2, v3};
    float4* outp = (float4*)(out + (size_t)b * SS) + tid;  // slot for t=0

    if (tid == 0) red2[0] = v0;   // g_0
    __syncthreads();
    float g1 = red2[0];
    float XpPrev = g1;
    float E0 = __expf(v0 - XpPrev), E1 = __expf(v1 - XpPrev);
    float E2 = __expf(v2 - XpPrev), E3 = __expf(v3 - XpPrev);
    {
        ushort4 E;
        E.x = f2b(E0); E.y = f2b(E1); E.z = f2b(E2); E.w = f2b(E3);
        *(ushort4*)(&Ebuf[0][GUARD_L + 4 * tid]) = E;
    }

    emp += (BB * SS) / 4;
    float4 em_next = *emp;   // t=1

    // ---- steps 1..L-1: one raw barrier per step; out-store one step behind ----
    int cur = 0;
    for (int t = 1; t < LL; t++) {
        BAR();
        *outp = ov_prev;                    // store v_{t-1}; ack never drained in-loop
        outp += (BB * SS) / 4;

        em = em_next;
        if (t < LL - 1) { emp += (BB * SS) / 4; em_next = *emp; }

        float g0 = red2[cur];
        float Xp = 2.f * g0 - g1;

        const unsigned short* Eb = Ebuf[cur] + GUARD_L + 4 * tid;
        ushort4 YpU = *(const ushort4*)(Eb + 16);
        ushort4 YmU = *(const ushort4*)(Eb - 16);
        ushort4 ZpU = *(const ushort4*)(Eb + 256);
        ushort4 ZqU = *(const ushort4*)(Eb + 512);
        float bx  = b2f(Eb[4]);
        float cxw = b2f(Eb[-1]);

        float a0 = E0*pw[0]  + E1*pw[1]  + cxw*pw[2] + b2f(YpU.x)*pw[3]  + b2f(YmU.x)*pw[4]  + b2f(ZpU.x)*pw[5]  + b2f(ZqU.x)*pw[6];
        float a1 = E1*pw[7]  + E2*pw[8]  + E0*pw[9]  + b2f(YpU.y)*pw[10] + b2f(YmU.y)*pw[11] + b2f(ZpU.y)*pw[12] + b2f(ZqU.y)*pw[13];
        float a2 = E2*pw[14] + E3*pw[15] + E1*pw[16] + b2f(YpU.z)*pw[17] + b2f(YmU.z)*pw[18] + b2f(ZpU.z)*pw[19] + b2f(ZqU.z)*pw[20];
        float a3 = E3*pw[21] + bx*pw[22] + E2*pw[23] + b2f(YpU.w)*pw[24] + b2f(YmU.w)*pw[25] + b2f(ZpU.w)*pw[26] + b2f(ZqU.w)*pw[27];

        v0 = em.x + __logf(a0) + XpPrev + am[0];
        v1 = em.y + __logf(a1) + XpPrev + am[1];
        v2 = em.z + __logf(a2) + XpPrev + am[2];
        v3 = em.w + __logf(a3) + XpPrev + am[3];
        ov_prev.x = v0; ov_prev.y = v1; ov_prev.z = v2; ov_prev.w = v3;

        E0 = __expf(v0 - Xp); E1 = __expf(v1 - Xp);
        E2 = __expf(v2 - Xp); E3 = __expf(v3 - Xp);
        {
            ushort4 E;
            E.x = f2b(E0); E.y = f2b(E1); E.z = f2b(E2); E.w = f2b(E3);
            *(ushort4*)(&Ebuf[cur ^ 1][GUARD_L + 4 * tid]) = E;
        }
        if (tid == 0) red2[cur ^ 1] = v0;  // g_t

        g1 = g0; XpPrev = Xp; cur ^= 1;
    }
    *outp = ov_prev;   // t = LL-1
}

extern "C" void kernel_launch(void* const* d_in, const int* in_sizes, int n_in,
                              void* d_out, int out_size, void* d_ws, size_t ws_size,
                              hipStream_t stream) {
    const int*   stories = (const int*)d_in[0];
    const float* trans_w = (const float*)d_in[2];
    const float* emis_w  = (const float*)d_in[3];
    const float* prior_w = (const float*)d_in[4];
    float* out = (float*)d_out;

    char* ws = (char*)d_ws;
    unsigned short* smTb = (unsigned short*)(ws);                          // 16 MB bf16
    float* all_emis = (float*)(ws + (size_t)VV * SS * 2);                  // 4 MB
    float* logZ     = (float*)(ws + (size_t)VV * SS * 2 + (size_t)LL * BB * SS * 4);  // 16 KB

    k_logZ<<<SS / 4, 256, 0, stream>>>(emis_w, logZ);
    k_smooth<<<dim3(ZD, VV / VC), 256, 0, stream>>>(emis_w, logZ, smTb);
    k_emis<<<LL * BB, 512, 0, stream>>>(stories, smTb, all_emis);
    k_forward<<<BB, 1024, 0, stream>>>(trans_w, prior_w, all_emis, out);
}